// Round 3
// baseline (15448.010 us; speedup 1.0000x reference)
//
#include <hip/hip_runtime.h>
#include <math.h>
#include <stdint.h>

#define C_ 8
#define K_ 64
#define D_ 32
#define N_ 2048

// ---- packed per-(c,k) weight chunk (floats), CH floats each ----
#define CH   4352  // 4320 used + 32 pad (staged, never read)
#define OW1S 0     // W1s packed [64][16]  (used input cols only)
#define OW2S 1024  // W2s packed [16][64]  (updated output rows only)
#define OW1T 2048
#define OW2T 3072
#define OB1S 4096  // [64]
#define OB1T 4160  // [64]
#define OB2S 4224  // [16] packed (updated rows)
#define OB2T 4240  // [16]
#define OAT  4256  // at_even[16], at_odd[16]
#define OEA  4288  // ea_even[16], ea_odd[16]

#define SMEM_FLOATS (2 * CH + 16384)
#define SMEM_BYTES  (SMEM_FLOATS * 4)   // 100352 B

// ws layout (floats): els[256] @0, CONST[8] @256, logp @512, Bn @16896, A @33280

typedef __attribute__((address_space(3))) uint32_t       lds_u32_t;
typedef const __attribute__((address_space(1))) uint32_t gbl_u32_t;

__device__ __forceinline__ void gld_lds16(const float* g, float* l) {
  __builtin_amdgcn_global_load_lds((gbl_u32_t*)g, (lds_u32_t*)l, 16, 0, 0);
}

// stage one 4352-float chunk: 4 full sweeps (256 lanes x 16B) + 1 quarter sweep
__device__ __forceinline__ void stage_chunk(const float* __restrict__ g,
                                            float* l, int w, int lane) {
#pragma unroll
  for (int it = 0; it < 4; ++it) {
    gld_lds16(g + (it * 256 + w * 64 + lane) * 4, l + it * 1024 + w * 256);
  }
  if (w == 0) gld_lds16(g + (1024 + lane) * 4, l + 4096);
}

// ---------------- packing ----------------
__global__ __launch_bounds__(256) void k_pack(
    const float* __restrict__ sW1, const float* __restrict__ sb1,
    const float* __restrict__ sW2, const float* __restrict__ sb2,
    const float* __restrict__ tW1, const float* __restrict__ tb1,
    const float* __restrict__ tW2, const float* __restrict__ tb2,
    const float* __restrict__ an_s, const float* __restrict__ an_t,
    float* __restrict__ pk) {
  const int b = blockIdx.x;  // = c*64 + k
  const int k = b & 63, pin = k & 1;
  const int ck = b;
  float* dst = pk + (size_t)b * CH;
  const int t = threadIdx.x;
  {  // W1 gather: j = t>>2 in [0,64), quad q
    const int j = t >> 2, q = (t & 3) << 2;
    const float* s1 = sW1 + ck * 2048 + j * 32 + pin;
    const float* t1 = tW1 + ck * 2048 + j * 32 + pin;
    float4 vs = make_float4(s1[2 * q], s1[2 * q + 2], s1[2 * q + 4], s1[2 * q + 6]);
    float4 vt = make_float4(t1[2 * q], t1[2 * q + 2], t1[2 * q + 4], t1[2 * q + 6]);
    *(float4*)(dst + OW1S + j * 16 + q) = vs;
    *(float4*)(dst + OW1T + j * 16 + q) = vt;
  }
  {  // W2 gather: o = t>>4 in [0,16), jq
    const int o = t >> 4, jq = (t & 15) << 2;
    const int row = 2 * o + 1 - pin;
    const float4 vs = *(const float4*)(sW2 + ck * 2048 + row * 64 + jq);
    const float4 vt = *(const float4*)(tW2 + ck * 2048 + row * 64 + jq);
    *(float4*)(dst + OW2S + o * 64 + jq) = vs;
    *(float4*)(dst + OW2T + o * 64 + jq) = vt;
  }
  if (t < 64) {
    dst[OB1S + t] = sb1[ck * 64 + t];
    dst[OB1T + t] = tb1[ck * 64 + t];
  } else if (t < 80) {
    const int o = t - 64;
    dst[OB2S + o] = sb2[ck * 32 + 2 * o + 1 - pin];
    dst[OB2T + o] = tb2[ck * 32 + 2 * o + 1 - pin];
  } else if (t < 96) {
    const int i = t - 80;
    dst[OAT + i] = an_t[ck * 32 + 2 * i];
    dst[OAT + 16 + i] = an_t[ck * 32 + 2 * i + 1];
    dst[OEA + i] = expf(-an_s[ck * 32 + 2 * i]);
    dst[OEA + 16 + i] = expf(-an_s[ck * 32 + 2 * i + 1]);
  }
}

__global__ __launch_bounds__(256) void k_pre(const float* __restrict__ log_scale,
                                             float* __restrict__ ws) {
  int g = threadIdx.x;
  if (g < C_ * D_) ws[g] = expf(-log_scale[g]);
}

__global__ __launch_bounds__(512) void k_const(const float* __restrict__ an_s,
                                               const float* __restrict__ log_scale,
                                               float* __restrict__ ws) {
  int tid = threadIdx.x;
  int c = tid >> 6, lane = tid & 63;
  float acc = 0.f;
  for (int r = 0; r < 32; ++r) acc += an_s[c * 2048 + r * 64 + lane];
  if (lane < 32) acc += log_scale[c * 32 + lane];
  for (int off = 32; off; off >>= 1) acc += __shfl_down(acc, off);
  if (lane == 0) ws[256 + c] = -acc - 29.406033062549525f;  // 0.5*32*log(2pi)
}

// ---------------- flow layer ----------------
// x = kept parity (PIN), y = updated parity. Weights broadcast from LDS chunk wb.
// sched_barrier(0) every 2 rows bounds the scheduler's load-hoisting so weight
// values never pile up in VGPRs (round-2 lesson: unbounded hoist -> 256 VGPR +
// 11 GB scratch spill traffic).
template <int PIN>
__device__ __forceinline__ void layer_step(const float* wb, float* exb, int w,
                                           int idx0, float (&x)[16],
                                           float (&y)[16], float& ld) {
  const float* at_x = wb + OAT + 16 * PIN;
  const float* at_y = wb + OAT + 16 * (1 - PIN);
  const float* ea_x = wb + OEA + 16 * PIN;
  const float* ea_y = wb + OEA + 16 * (1 - PIN);
#pragma unroll
  for (int i = 0; i < 16; ++i) {
    x[i] = (x[i] - at_x[i]) * ea_x[i];
    y[i] = (y[i] - at_y[i]) * ea_y[i];
  }
  __builtin_amdgcn_sched_barrier(0);

  const int jb = w * 16;
  const int basew = idx0 ^ (w * 16);
  float h[16], p[16];

  // ---- s MLP ----
#pragma unroll
  for (int jj = 0; jj < 16; ++jj) {
    const float* wr = wb + OW1S + (jb + jj) * 16;
    float acc = wb[OB1S + jb + jj];
#pragma unroll
    for (int i = 0; i < 16; ++i) acc = fmaf(wr[i], x[i], acc);
    h[jj] = fmaxf(acc, 0.f);
    if (jj & 1) __builtin_amdgcn_sched_barrier(0);
  }
#pragma unroll
  for (int o = 0; o < 16; ++o) {
    const float* wr = wb + OW2S + o * 64 + jb;
    float acc = (w == 0) ? wb[OB2S + o] : 0.f;
#pragma unroll
    for (int jj = 0; jj < 16; ++jj) acc = fmaf(wr[jj], h[jj], acc);
    p[o] = acc;
    if (o & 1) __builtin_amdgcn_sched_barrier(0);
  }
#pragma unroll
  for (int q = 0; q < 4; ++q)
    *(float4*)(exb + (basew ^ (q * 4))) =
        make_float4(p[4 * q], p[4 * q + 1], p[4 * q + 2], p[4 * q + 3]);
  __builtin_amdgcn_sched_barrier(0);

  // ---- t MLP ----
#pragma unroll
  for (int jj = 0; jj < 16; ++jj) {
    const float* wr = wb + OW1T + (jb + jj) * 16;
    float acc = wb[OB1T + jb + jj];
#pragma unroll
    for (int i = 0; i < 16; ++i) acc = fmaf(wr[i], x[i], acc);
    h[jj] = fmaxf(acc, 0.f);
    if (jj & 1) __builtin_amdgcn_sched_barrier(0);
  }
#pragma unroll
  for (int o = 0; o < 16; ++o) {
    const float* wr = wb + OW2T + o * 64 + jb;
    float acc = (w == 0) ? wb[OB2T + o] : 0.f;
#pragma unroll
    for (int jj = 0; jj < 16; ++jj) acc = fmaf(wr[jj], h[jj], acc);
    p[o] = acc;
    if (o & 1) __builtin_amdgcn_sched_barrier(0);
  }
#pragma unroll
  for (int q = 0; q < 4; ++q)
    *(float4*)(exb + 4096 + (basew ^ (q * 4))) =
        make_float4(p[4 * q], p[4 * q + 1], p[4 * q + 2], p[4 * q + 3]);

  __syncthreads();  // drains vmcnt (staging) + lgkm, then s_barrier

  float sv[16], tv[16];
#pragma unroll
  for (int g = 0; g < 16; ++g) {
    float4 v = *(const float4*)(exb + (idx0 ^ (g * 4)));
    const int ob = (g & 3) * 4;
    if (g < 4) { sv[ob] = v.x; sv[ob + 1] = v.y; sv[ob + 2] = v.z; sv[ob + 3] = v.w; }
    else       { sv[ob] += v.x; sv[ob + 1] += v.y; sv[ob + 2] += v.z; sv[ob + 3] += v.w; }
    if ((g & 3) == 3) __builtin_amdgcn_sched_barrier(0);
  }
#pragma unroll
  for (int g = 0; g < 16; ++g) {
    float4 v = *(const float4*)(exb + 4096 + (idx0 ^ (g * 4)));
    const int ob = (g & 3) * 4;
    if (g < 4) { tv[ob] = v.x; tv[ob + 1] = v.y; tv[ob + 2] = v.z; tv[ob + 3] = v.w; }
    else       { tv[ob] += v.x; tv[ob + 1] += v.y; tv[ob + 2] += v.z; tv[ob + 3] += v.w; }
    if ((g & 3) == 3) __builtin_amdgcn_sched_barrier(0);
  }
#pragma unroll
  for (int o = 0; o < 16; ++o) {
    y[o] = (y[o] - tv[o]) * __expf(-sv[o]);
    ld -= sv[o];
  }
}

__global__ __launch_bounds__(256, 1) void k_flow(
    const float* __restrict__ nodes, const float* __restrict__ pk,
    const float* __restrict__ loc, const float* __restrict__ ws,
    float* __restrict__ logp) {
  extern __shared__ float smem[];
  float* wb = smem;             // 2*CH staging dbuf
  float* ex = smem + 2 * CH;    // 16384 exchange (2 parity x 2 mlp x 4096)

  const int lane = threadIdx.x;
  const int w = __builtin_amdgcn_readfirstlane((int)threadIdx.y);
  const int c = blockIdx.x & 7;        // component -> XCD (L2 locality)
  const int grp = blockIdx.x >> 3;
  const int node = grp * 64 + lane;

  float ze[16], zo[16];
  {
    const float4* np = (const float4*)(nodes + node * D_);
#pragma unroll
    for (int t = 0; t < 8; ++t) {
      float4 v = np[t];
      ze[2 * t] = v.x; zo[2 * t] = v.y; ze[2 * t + 1] = v.z; zo[2 * t + 1] = v.w;
    }
  }
  const int swzf = ((lane & 15) ^ (((lane >> 4) & 1) << 2)) * 4;
  const int idx0 = lane * 64 + swzf;
  float ld = 0.f;

  const float* chunks = pk + (size_t)c * (K_ * CH);
  stage_chunk(chunks + 63 * CH, wb, w, lane);
  __syncthreads();

  int cur = 0;
#pragma unroll 1
  for (int k = 63; k > 0; k -= 2) {
    stage_chunk(chunks + (k - 1) * CH, wb + (cur ^ 1) * CH, w, lane);
    layer_step<1>(wb + cur * CH, ex, w, idx0, zo, ze, ld);
    cur ^= 1;
    if (k > 1) stage_chunk(chunks + (k - 2) * CH, wb + (cur ^ 1) * CH, w, lane);
    layer_step<0>(wb + cur * CH, ex + 8192, w, idx0, ze, zo, ld);
    cur ^= 1;
  }

  if (w == 0) {
    const float* lc = loc + c * D_;
    const float* el = ws + c * D_;
    float sq = 0.f;
#pragma unroll
    for (int i = 0; i < 16; ++i) {
      float a = (ze[i] - lc[2 * i]) * el[2 * i];
      float b = (zo[i] - lc[2 * i + 1]) * el[2 * i + 1];
      sq += a * a + b * b;
    }
    logp[c * N_ + node] = ld + ws[256 + c] - 0.5f * sq;
  }
}

// ---------------- tail kernels ----------------
__global__ __launch_bounds__(256) void k_norm(const float* __restrict__ logp,
                                              float* __restrict__ Bn) {
  __shared__ float red[256];
  const int c = blockIdx.x;
  const int t = threadIdx.x;
  float e[8];
  float part = 0.f;
#pragma unroll
  for (int r = 0; r < 8; ++r) {
    e[r] = __expf(logp[c * N_ + r * 256 + t]);
    part += e[r];
  }
  red[t] = part;
  __syncthreads();
  for (int s = 128; s > 0; s >>= 1) {
    if (t < s) red[t] += red[t + s];
    __syncthreads();
  }
  const float inv = 1.f / fmaxf(red[0], 1e-12f);  // literal clamp, NO max-shift
#pragma unroll
  for (int r = 0; r < 8; ++r) Bn[c * N_ + r * 256 + t] = e[r] * inv;
}

__global__ __launch_bounds__(256) void k_A(const float* __restrict__ S_unc,
                                           const float* __restrict__ Bn,
                                           float* __restrict__ A) {
  __shared__ float sE[64];
  __shared__ float sInv;
  const int t = threadIdx.x;
  if (t < 64) sE[t] = __expf(S_unc[t]);
  __syncthreads();
  if (t == 0) {
    float tot = 0.f;
    for (int i = 0; i < 64; ++i) tot += sE[i];
    sInv = 1.f / tot;
  }
  __syncthreads();
  const int j = blockIdx.x * 256 + t;
  float b[8];
#pragma unroll
  for (int cc = 0; cc < 8; ++cc) b[cc] = Bn[cc * N_ + j];
#pragma unroll
  for (int c = 0; c < 8; ++c) {
    float acc = 0.f;
#pragma unroll
    for (int cc = 0; cc < 8; ++cc) acc += sE[c * 8 + cc] * b[cc];
    A[c * N_ + j] = acc * sInv;
  }
}

__global__ __launch_bounds__(256) void k_out(const float* __restrict__ Bn,
                                             const float* __restrict__ A,
                                             float* __restrict__ out) {
  const int T = blockIdx.x * 256 + threadIdx.x;
  const int i0 = (T >> 9) << 2;
  const int j0 = (T & 511) << 2;
  float acc[4][4];
#pragma unroll
  for (int r = 0; r < 4; ++r)
#pragma unroll
    for (int e2 = 0; e2 < 4; ++e2) acc[r][e2] = 0.f;
#pragma unroll
  for (int cc = 0; cc < 8; ++cc) {
    const float4 bi = *(const float4*)(Bn + cc * N_ + i0);
    const float4 aj = *(const float4*)(A + cc * N_ + j0);
    const float br[4] = {bi.x, bi.y, bi.z, bi.w};
    const float ar[4] = {aj.x, aj.y, aj.z, aj.w};
#pragma unroll
    for (int r = 0; r < 4; ++r)
#pragma unroll
      for (int e2 = 0; e2 < 4; ++e2) acc[r][e2] += br[r] * ar[e2];
  }
#pragma unroll
  for (int r = 0; r < 4; ++r)
    *(float4*)(out + (i0 + r) * N_ + j0) =
        make_float4(acc[r][0], acc[r][1], acc[r][2], acc[r][3]);
}

extern "C" void kernel_launch(void* const* d_in, const int* in_sizes, int n_in,
                              void* d_out, int out_size, void* d_ws,
                              size_t ws_size, hipStream_t stream) {
  const float* nodes = (const float*)d_in[0];
  const float* sW1 = (const float*)d_in[1];
  const float* sb1 = (const float*)d_in[2];
  const float* sW2 = (const float*)d_in[3];
  const float* sb2 = (const float*)d_in[4];
  const float* tW1 = (const float*)d_in[5];
  const float* tb1 = (const float*)d_in[6];
  const float* tW2 = (const float*)d_in[7];
  const float* tb2 = (const float*)d_in[8];
  const float* an_s = (const float*)d_in[9];
  const float* an_t = (const float*)d_in[10];
  const float* loc = (const float*)d_in[11];
  const float* log_scale = (const float*)d_in[12];
  const float* S_unc = (const float*)d_in[13];
  float* out = (float*)d_out;
  float* ws = (float*)d_ws;

  // packed weights live in d_out (8.9 MB of 16.8 MB); overwritten by k_out last
  float* pkw = out;
  float* logp = ws + 512;
  float* Bn = ws + 16896;
  float* A = ws + 33280;

  k_pack<<<512, 256, 0, stream>>>(sW1, sb1, sW2, sb2, tW1, tb1, tW2, tb2,
                                  an_s, an_t, pkw);
  k_pre<<<1, 256, 0, stream>>>(log_scale, ws);
  k_const<<<1, 512, 0, stream>>>(an_s, log_scale, ws);

  hipFuncSetAttribute((const void*)k_flow,
                      hipFuncAttributeMaxDynamicSharedMemorySize, SMEM_BYTES);
  k_flow<<<256, dim3(64, 4), SMEM_BYTES, stream>>>(nodes, pkw, loc, ws, logp);

  k_norm<<<8, 256, 0, stream>>>(logp, Bn);
  k_A<<<8, 256, 0, stream>>>(S_unc, Bn, A);
  k_out<<<1024, 256, 0, stream>>>(Bn, A, out);
}

// Round 4
// 637.857 us; speedup vs baseline: 24.2186x; 24.2186x over previous
//
#include <hip/hip_runtime.h>
#include <math.h>
#include <stdint.h>

#define C_ 8
#define K_ 64
#define D_ 32
#define N_ 2048

// ---- packed per-(c,k) weight chunk (floats), CH floats each ----
#define CH   4352  // 4320 used + 32 pad
#define OW1S 0     // W1s packed [64][16]  (used input cols only)
#define OW2S 1024  // W2s packed [16][64]  (updated output rows only)
#define OW1T 2048
#define OW2T 3072
#define OB1S 4096  // [64]
#define OB1T 4160  // [64]
#define OB2S 4224  // [16] packed (updated rows)
#define OB2T 4240  // [16]
#define OAT  4256  // at_even[16], at_odd[16]
#define OEA  4288  // ea_even[16], ea_odd[16]

// ws layout (floats): els[256] @0, CONST[8] @256, logp @512, Bn @16896, A @33280

// ---------------- packing ----------------
__global__ __launch_bounds__(256) void k_pack(
    const float* __restrict__ sW1, const float* __restrict__ sb1,
    const float* __restrict__ sW2, const float* __restrict__ sb2,
    const float* __restrict__ tW1, const float* __restrict__ tb1,
    const float* __restrict__ tW2, const float* __restrict__ tb2,
    const float* __restrict__ an_s, const float* __restrict__ an_t,
    float* __restrict__ pk) {
  const int b = blockIdx.x;  // = c*64 + k
  const int k = b & 63, pin = k & 1;
  const int ck = b;
  float* dst = pk + (size_t)b * CH;
  const int t = threadIdx.x;
  {  // W1 gather: j = t>>2 in [0,64), quad q
    const int j = t >> 2, q = (t & 3) << 2;
    const float* s1 = sW1 + ck * 2048 + j * 32 + pin;
    const float* t1 = tW1 + ck * 2048 + j * 32 + pin;
    float4 vs = make_float4(s1[2 * q], s1[2 * q + 2], s1[2 * q + 4], s1[2 * q + 6]);
    float4 vt = make_float4(t1[2 * q], t1[2 * q + 2], t1[2 * q + 4], t1[2 * q + 6]);
    *(float4*)(dst + OW1S + j * 16 + q) = vs;
    *(float4*)(dst + OW1T + j * 16 + q) = vt;
  }
  {  // W2 gather: o = t>>4 in [0,16), jq
    const int o = t >> 4, jq = (t & 15) << 2;
    const int row = 2 * o + 1 - pin;
    const float4 vs = *(const float4*)(sW2 + ck * 2048 + row * 64 + jq);
    const float4 vt = *(const float4*)(tW2 + ck * 2048 + row * 64 + jq);
    *(float4*)(dst + OW2S + o * 64 + jq) = vs;
    *(float4*)(dst + OW2T + o * 64 + jq) = vt;
  }
  if (t < 64) {
    dst[OB1S + t] = sb1[ck * 64 + t];
    dst[OB1T + t] = tb1[ck * 64 + t];
  } else if (t < 80) {
    const int o = t - 64;
    dst[OB2S + o] = sb2[ck * 32 + 2 * o + 1 - pin];
    dst[OB2T + o] = tb2[ck * 32 + 2 * o + 1 - pin];
  } else if (t < 96) {
    const int i = t - 80;
    dst[OAT + i] = an_t[ck * 32 + 2 * i];
    dst[OAT + 16 + i] = an_t[ck * 32 + 2 * i + 1];
    dst[OEA + i] = expf(-an_s[ck * 32 + 2 * i]);
    dst[OEA + 16 + i] = expf(-an_s[ck * 32 + 2 * i + 1]);
  }
}

__global__ __launch_bounds__(256) void k_pre(const float* __restrict__ log_scale,
                                             float* __restrict__ ws) {
  int g = threadIdx.x;
  if (g < C_ * D_) ws[g] = expf(-log_scale[g]);
}

__global__ __launch_bounds__(512) void k_const(const float* __restrict__ an_s,
                                               const float* __restrict__ log_scale,
                                               float* __restrict__ ws) {
  int tid = threadIdx.x;
  int c = tid >> 6, lane = tid & 63;
  float acc = 0.f;
  for (int r = 0; r < 32; ++r) acc += an_s[c * 2048 + r * 64 + lane];
  if (lane < 32) acc += log_scale[c * 32 + lane];
  for (int off = 32; off; off >>= 1) acc += __shfl_down(acc, off);
  if (lane == 0) ws[256 + c] = -acc - 29.406033062549525f;  // 0.5*32*log(2pi)
}

// ---------------- flow layer pieces ----------------
// fwd: actnorm both parities, two MLPs using x, write GEMM2 partials to ex.
template <int PIN>
__device__ __forceinline__ void layer_fwd(const float* wb, float* ex, int w,
                                          int idx0, float (&x)[16],
                                          float (&y)[16]) {
  const float* at_x = wb + OAT + 16 * PIN;
  const float* at_y = wb + OAT + 16 * (1 - PIN);
  const float* ea_x = wb + OEA + 16 * PIN;
  const float* ea_y = wb + OEA + 16 * (1 - PIN);
#pragma unroll
  for (int i = 0; i < 16; ++i) {
    x[i] = (x[i] - at_x[i]) * ea_x[i];
    y[i] = (y[i] - at_y[i]) * ea_y[i];
  }

  const int jb = w * 16;
  const int basew = idx0 ^ (w * 16);
  float h[16], p[16];

  // ---- s MLP ----
#pragma unroll
  for (int jj = 0; jj < 16; ++jj) {
    const float* wr = wb + OW1S + (jb + jj) * 16;
    float acc = wb[OB1S + jb + jj];
#pragma unroll
    for (int i = 0; i < 16; ++i) acc = fmaf(wr[i], x[i], acc);
    h[jj] = fmaxf(acc, 0.f);
  }
#pragma unroll
  for (int o = 0; o < 16; ++o) {
    const float* wr = wb + OW2S + o * 64 + jb;
    float acc = (w == 0) ? wb[OB2S + o] : 0.f;
#pragma unroll
    for (int jj = 0; jj < 16; ++jj) acc = fmaf(wr[jj], h[jj], acc);
    p[o] = acc;
  }
#pragma unroll
  for (int q = 0; q < 4; ++q)
    *(float4*)(ex + (basew ^ (q * 4))) =
        make_float4(p[4 * q], p[4 * q + 1], p[4 * q + 2], p[4 * q + 3]);

  // ---- t MLP ----
#pragma unroll
  for (int jj = 0; jj < 16; ++jj) {
    const float* wr = wb + OW1T + (jb + jj) * 16;
    float acc = wb[OB1T + jb + jj];
#pragma unroll
    for (int i = 0; i < 16; ++i) acc = fmaf(wr[i], x[i], acc);
    h[jj] = fmaxf(acc, 0.f);
  }
#pragma unroll
  for (int o = 0; o < 16; ++o) {
    const float* wr = wb + OW2T + o * 64 + jb;
    float acc = (w == 0) ? wb[OB2T + o] : 0.f;
#pragma unroll
    for (int jj = 0; jj < 16; ++jj) acc = fmaf(wr[jj], h[jj], acc);
    p[o] = acc;
  }
#pragma unroll
  for (int q = 0; q < 4; ++q)
    *(float4*)(ex + 4096 + (basew ^ (q * 4))) =
        make_float4(p[4 * q], p[4 * q + 1], p[4 * q + 2], p[4 * q + 3]);
}

// fin: reduce 4-wave partials from ex, apply affine update to y, accumulate ld.
__device__ __forceinline__ void layer_fin(const float* ex, int idx0,
                                          float (&y)[16], float& ld) {
  float sv[16], tv[16];
#pragma unroll
  for (int g = 0; g < 16; ++g) {
    float4 v = *(const float4*)(ex + (idx0 ^ (g * 4)));
    const int ob = (g & 3) * 4;
    if (g < 4) { sv[ob] = v.x; sv[ob + 1] = v.y; sv[ob + 2] = v.z; sv[ob + 3] = v.w; }
    else       { sv[ob] += v.x; sv[ob + 1] += v.y; sv[ob + 2] += v.z; sv[ob + 3] += v.w; }
  }
#pragma unroll
  for (int g = 0; g < 16; ++g) {
    float4 v = *(const float4*)(ex + 4096 + (idx0 ^ (g * 4)));
    const int ob = (g & 3) * 4;
    if (g < 4) { tv[ob] = v.x; tv[ob + 1] = v.y; tv[ob + 2] = v.z; tv[ob + 3] = v.w; }
    else       { tv[ob] += v.x; tv[ob + 1] += v.y; tv[ob + 2] += v.z; tv[ob + 3] += v.w; }
  }
#pragma unroll
  for (int o = 0; o < 16; ++o) {
    y[o] = (y[o] - tv[o]) * __expf(-sv[o]);
    ld -= sv[o];
  }
}

__global__ __launch_bounds__(256, 1) void k_flow(
    const float* __restrict__ nodes, const float* __restrict__ pk,
    const float* __restrict__ loc, const float* __restrict__ ws,
    float* __restrict__ logp) {
  __shared__ float wb[CH];     // single weight buffer (static LDS)
  __shared__ float ex[8192];   // single exchange buffer: s @0, t @4096

  const int lane = threadIdx.x;
  const int w = __builtin_amdgcn_readfirstlane((int)threadIdx.y);
  const int t = w * 64 + lane;         // 0..255, staging id
  const int c = blockIdx.x & 7;        // component -> XCD (L2 locality)
  const int grp = blockIdx.x >> 3;
  const int node = grp * 64 + lane;

  float ze[16], zo[16];
  {
    const float4* np = (const float4*)(nodes + node * D_);
#pragma unroll
    for (int q = 0; q < 8; ++q) {
      float4 v = np[q];
      ze[2 * q] = v.x; zo[2 * q] = v.y; ze[2 * q + 1] = v.z; zo[2 * q + 1] = v.w;
    }
  }
  const int swzf = ((lane & 15) ^ (((lane >> 4) & 1) << 2)) * 4;
  const int idx0 = lane * 64 + swzf;
  float ld = 0.f;

  const float* chunks = pk + (size_t)c * (K_ * CH);

  // prologue: stage chunk 63 (coalesced float4 sweeps + scalar tail)
  {
    const float4* g4 = (const float4*)(chunks + 63 * CH);
#pragma unroll
    for (int q = 0; q < 4; ++q) ((float4*)wb)[q * 256 + t] = g4[q * 256 + t];
    wb[4096 + t] = chunks[63 * CH + 4096 + t];
  }
  __syncthreads();

#pragma unroll 1
  for (int k = 63; k > 0; k -= 2) {
    // ---------- layer k (PIN=1): x=zo kept, y=ze updated ----------
    float4 r0, r1, r2, r3;
    float r4;
    {  // issue prefetch of chunk k-1 (plain coalesced loads into regs)
      const float4* g4 = (const float4*)(chunks + (k - 1) * CH);
      r0 = g4[0 * 256 + t]; r1 = g4[1 * 256 + t];
      r2 = g4[2 * 256 + t]; r3 = g4[3 * 256 + t];
      r4 = chunks[(k - 1) * CH + 4096 + t];
    }
    layer_fwd<1>(wb, ex, w, idx0, zo, ze);
    __syncthreads();                 // partials visible; wb reads done
    layer_fin(ex, idx0, ze, ld);
    ((float4*)wb)[0 * 256 + t] = r0; ((float4*)wb)[1 * 256 + t] = r1;
    ((float4*)wb)[2 * 256 + t] = r2; ((float4*)wb)[3 * 256 + t] = r3;
    wb[4096 + t] = r4;
    __syncthreads();                 // wb=chunk k-1; ex reads done

    // ---------- layer k-1 (PIN=0): x=ze kept, y=zo updated ----------
    const bool more = (k >= 3);
    if (more) {
      const float4* g4 = (const float4*)(chunks + (k - 2) * CH);
      r0 = g4[0 * 256 + t]; r1 = g4[1 * 256 + t];
      r2 = g4[2 * 256 + t]; r3 = g4[3 * 256 + t];
      r4 = chunks[(k - 2) * CH + 4096 + t];
    }
    layer_fwd<0>(wb, ex, w, idx0, ze, zo);
    __syncthreads();
    layer_fin(ex, idx0, zo, ld);
    if (more) {
      ((float4*)wb)[0 * 256 + t] = r0; ((float4*)wb)[1 * 256 + t] = r1;
      ((float4*)wb)[2 * 256 + t] = r2; ((float4*)wb)[3 * 256 + t] = r3;
      wb[4096 + t] = r4;
    }
    __syncthreads();
  }

  if (w == 0) {
    const float* lc = loc + c * D_;
    const float* el = ws + c * D_;
    float sq = 0.f;
#pragma unroll
    for (int i = 0; i < 16; ++i) {
      float a = (ze[i] - lc[2 * i]) * el[2 * i];
      float b = (zo[i] - lc[2 * i + 1]) * el[2 * i + 1];
      sq += a * a + b * b;
    }
    logp[c * N_ + node] = ld + ws[256 + c] - 0.5f * sq;
  }
}

// ---------------- tail kernels ----------------
__global__ __launch_bounds__(256) void k_norm(const float* __restrict__ logp,
                                              float* __restrict__ Bn) {
  __shared__ float red[256];
  const int c = blockIdx.x;
  const int t = threadIdx.x;
  float e[8];
  float part = 0.f;
#pragma unroll
  for (int r = 0; r < 8; ++r) {
    e[r] = __expf(logp[c * N_ + r * 256 + t]);
    part += e[r];
  }
  red[t] = part;
  __syncthreads();
  for (int s = 128; s > 0; s >>= 1) {
    if (t < s) red[t] += red[t + s];
    __syncthreads();
  }
  const float inv = 1.f / fmaxf(red[0], 1e-12f);  // literal clamp, NO max-shift
#pragma unroll
  for (int r = 0; r < 8; ++r) Bn[c * N_ + r * 256 + t] = e[r] * inv;
}

__global__ __launch_bounds__(256) void k_A(const float* __restrict__ S_unc,
                                           const float* __restrict__ Bn,
                                           float* __restrict__ A) {
  __shared__ float sE[64];
  __shared__ float sInv;
  const int t = threadIdx.x;
  if (t < 64) sE[t] = __expf(S_unc[t]);
  __syncthreads();
  if (t == 0) {
    float tot = 0.f;
    for (int i = 0; i < 64; ++i) tot += sE[i];
    sInv = 1.f / tot;
  }
  __syncthreads();
  const int j = blockIdx.x * 256 + t;
  float b[8];
#pragma unroll
  for (int cc = 0; cc < 8; ++cc) b[cc] = Bn[cc * N_ + j];
#pragma unroll
  for (int c = 0; c < 8; ++c) {
    float acc = 0.f;
#pragma unroll
    for (int cc = 0; cc < 8; ++cc) acc += sE[c * 8 + cc] * b[cc];
    A[c * N_ + j] = acc * sInv;
  }
}

__global__ __launch_bounds__(256) void k_out(const float* __restrict__ Bn,
                                             const float* __restrict__ A,
                                             float* __restrict__ out) {
  const int T = blockIdx.x * 256 + threadIdx.x;
  const int i0 = (T >> 9) << 2;
  const int j0 = (T & 511) << 2;
  float acc[4][4];
#pragma unroll
  for (int r = 0; r < 4; ++r)
#pragma unroll
    for (int e2 = 0; e2 < 4; ++e2) acc[r][e2] = 0.f;
#pragma unroll
  for (int cc = 0; cc < 8; ++cc) {
    const float4 bi = *(const float4*)(Bn + cc * N_ + i0);
    const float4 aj = *(const float4*)(A + cc * N_ + j0);
    const float br[4] = {bi.x, bi.y, bi.z, bi.w};
    const float ar[4] = {aj.x, aj.y, aj.z, aj.w};
#pragma unroll
    for (int r = 0; r < 4; ++r)
#pragma unroll
      for (int e2 = 0; e2 < 4; ++e2) acc[r][e2] += br[r] * ar[e2];
  }
#pragma unroll
  for (int r = 0; r < 4; ++r)
    *(float4*)(out + (i0 + r) * N_ + j0) =
        make_float4(acc[r][0], acc[r][1], acc[r][2], acc[r][3]);
}

extern "C" void kernel_launch(void* const* d_in, const int* in_sizes, int n_in,
                              void* d_out, int out_size, void* d_ws,
                              size_t ws_size, hipStream_t stream) {
  const float* nodes = (const float*)d_in[0];
  const float* sW1 = (const float*)d_in[1];
  const float* sb1 = (const float*)d_in[2];
  const float* sW2 = (const float*)d_in[3];
  const float* sb2 = (const float*)d_in[4];
  const float* tW1 = (const float*)d_in[5];
  const float* tb1 = (const float*)d_in[6];
  const float* tW2 = (const float*)d_in[7];
  const float* tb2 = (const float*)d_in[8];
  const float* an_s = (const float*)d_in[9];
  const float* an_t = (const float*)d_in[10];
  const float* loc = (const float*)d_in[11];
  const float* log_scale = (const float*)d_in[12];
  const float* S_unc = (const float*)d_in[13];
  float* out = (float*)d_out;
  float* ws = (float*)d_ws;

  // packed weights live in d_out (8.9 MB of 16.8 MB); overwritten by k_out last
  float* pkw = out;
  float* logp = ws + 512;
  float* Bn = ws + 16896;
  float* A = ws + 33280;

  k_pack<<<512, 256, 0, stream>>>(sW1, sb1, sW2, sb2, tW1, tb1, tW2, tb2,
                                  an_s, an_t, pkw);
  k_pre<<<1, 256, 0, stream>>>(log_scale, ws);
  k_const<<<1, 512, 0, stream>>>(an_s, log_scale, ws);

  k_flow<<<256, dim3(64, 4), 0, stream>>>(nodes, pkw, loc, ws, logp);

  k_norm<<<8, 256, 0, stream>>>(logp, Bn);
  k_A<<<8, 256, 0, stream>>>(S_unc, Bn, A);
  k_out<<<1024, 256, 0, stream>>>(Bn, A, out);
}